// Round 1
// baseline (32104.556 us; speedup 1.0000x reference)
//
#include <hip/hip_runtime.h>

#define Bn 256
#define Sn 512
#define En 512
#define Hn 1024
#define HMn 512

typedef _Float16 f16;
typedef _Float16 f16x8 __attribute__((ext_vector_type(8)));
typedef _Float16 f16x4 __attribute__((ext_vector_type(4)));
typedef float f32x4 __attribute__((ext_vector_type(4)));

// ---------------- prep kernels ----------------

__global__ void transpose_cvt(const float* __restrict__ src, f16* __restrict__ dst, int R, int C) {
  int idx = blockIdx.x * 256 + threadIdx.x;
  if (idx >= R * C) return;
  int r = idx / C, c = idx % C;
  dst[(size_t)c * R + r] = (f16)src[idx];
}

__global__ void init_zero(f16* hbuf, int* ctrs) {
  int idx = blockIdx.x * 256 + threadIdx.x;
  if (idx < (Bn * Hn) / 8) ((uint4*)hbuf)[idx] = make_uint4(0u, 0u, 0u, 0u);
  if (idx < 16 * 64) ctrs[idx] = 0;
}

// ---------------- phase A: xh = relu(seq@w1x+b1x)@w2x+b2x ----------------
// 128x128 tile, BK=32, 4 waves x (4x4) 16x16x32 f16 MFMA frags.
// BT is [N][K] f16 (pre-transposed weights).

template <bool A_FP32, bool RELU, bool OUT_F16>
__global__ __launch_bounds__(256) void gemm128(
    const void* __restrict__ Av, const f16* __restrict__ BT,
    const float* __restrict__ bias, void* __restrict__ Cv,
    int M, int N, int K) {
  __shared__ f16 As[128][40];  // +8 pad: 2-way bank alias only (free)
  __shared__ f16 Bs[128][40];
  const int m0 = blockIdx.x * 128, n0 = blockIdx.y * 128;
  const int tid = threadIdx.x;
  const int wave = tid >> 6, lane = tid & 63, quad = lane >> 4, l16 = lane & 15;
  const int wm = (wave & 1) * 64, wn = (wave >> 1) * 64;

  f32x4 acc[4][4] = {};

  for (int k0 = 0; k0 < K; k0 += 32) {
    if (A_FP32) {
      const float* A = (const float*)Av;
#pragma unroll
      for (int i = 0; i < 4; ++i) {
        int slot = tid + i * 256;
        int row = slot >> 3, c4 = (slot & 7) * 4;
        float4 v = *(const float4*)(A + (size_t)(m0 + row) * K + k0 + c4);
        f16x4 h;
        h[0] = (f16)v.x; h[1] = (f16)v.y; h[2] = (f16)v.z; h[3] = (f16)v.w;
        *(f16x4*)&As[row][c4] = h;
      }
    } else {
      const f16* A = (const f16*)Av;
#pragma unroll
      for (int i = 0; i < 2; ++i) {
        int slot = tid + i * 256;
        int row = slot >> 2, c8 = (slot & 3) * 8;
        *(uint4*)&As[row][c8] = *(const uint4*)(A + (size_t)(m0 + row) * K + k0 + c8);
      }
    }
#pragma unroll
    for (int i = 0; i < 2; ++i) {
      int slot = tid + i * 256;
      int row = slot >> 2, c8 = (slot & 3) * 8;
      *(uint4*)&Bs[row][c8] = *(const uint4*)(BT + (size_t)(n0 + row) * K + k0 + c8);
    }
    __syncthreads();
    f16x8 af[4];
#pragma unroll
    for (int mi = 0; mi < 4; ++mi)
      af[mi] = *(const f16x8*)&As[wm + mi * 16 + l16][quad * 8];
#pragma unroll
    for (int ni = 0; ni < 4; ++ni) {
      f16x8 bf = *(const f16x8*)&Bs[wn + ni * 16 + l16][quad * 8];
#pragma unroll
      for (int mi = 0; mi < 4; ++mi)
        acc[mi][ni] = __builtin_amdgcn_mfma_f32_16x16x32_f16(af[mi], bf, acc[mi][ni], 0, 0, 0);
    }
    __syncthreads();
  }
#pragma unroll
  for (int ni = 0; ni < 4; ++ni) {
    int col = n0 + wn + ni * 16 + l16;
    float bv = bias[col];
#pragma unroll
    for (int mi = 0; mi < 4; ++mi) {
#pragma unroll
      for (int r = 0; r < 4; ++r) {
        int grow = m0 + wm + mi * 16 + quad * 4 + r;
        float v = acc[mi][ni][r] + bv;
        if (RELU) v = fmaxf(v, 0.f);
        if (OUT_F16)
          ((f16*)Cv)[(size_t)grow * N + col] = (f16)v;
        else
          ((float*)Cv)[(size_t)grow * N + col] = v;
      }
    }
  }
}

// ---------------- phase B: the recurrence ----------------
// 256 WGs: group g = bid&15 owns rows [16g,16g+16); member j = bid>>4 owns
// C1 cols [32j,32j+32) and H cols [64j,64j+64). Weight slices LDS-resident.
// 4 waves split K; wave 0 reduces partials (LDS) and does the epilogue.

#define W1S_ELEMS (32 * 1032)
#define W2S_ELEMS (64 * 520)
#define RED_OFF (W1S_ELEMS * 2 + W2S_ELEMS * 2)
#define RECUR_SMEM (RED_OFF + 12 * 16 * 24 * 4)

__global__ __launch_bounds__(256, 1) void recur(
    const f16* __restrict__ w1hT, const f16* __restrict__ w2hT,
    const float* __restrict__ b1h, const float* __restrict__ b2h,
    const int* __restrict__ lens,
    f16* hbuf, f16* c1buf, float* out, int* ctrs) {
  extern __shared__ char smem[];
  f16* w1s = (f16*)smem;                   // [32][1032] (pad 8)
  f16* w2s = (f16*)(smem + W1S_ELEMS * 2); // [64][520]  (pad 8)
  float* red = (float*)(smem + RED_OFF);   // [12][16][24]

  const int g = blockIdx.x & 15, j = blockIdx.x >> 4;
  const int r0 = g * 16, c1_0 = j * 32, c2_0 = j * 64;
  const int tid = threadIdx.x, wave = tid >> 6, lane = tid & 63;
  const int quad = lane >> 4, l16 = lane & 15;
  int* ctr = ctrs + g * 64;

  // load weight slices into LDS once
#pragma unroll
  for (int i = 0; i < 16; ++i) {
    int slot = tid + i * 256;
    int row = slot >> 7, c8 = (slot & 127) * 8;
    *(uint4*)&w1s[row * 1032 + c8] = *(const uint4*)&w1hT[(size_t)(c1_0 + row) * 1024 + c8];
  }
#pragma unroll
  for (int i = 0; i < 16; ++i) {
    int slot = tid + i * 256;
    int row = slot >> 6, c8 = (slot & 63) * 8;
    *(uint4*)&w2s[row * 520 + c8] = *(const uint4*)&w2hT[(size_t)(c2_0 + row) * 512 + c8];
  }

  float b1v[2], b2v[4], h_own[4][4];
  int len4[4];
#pragma unroll
  for (int nf = 0; nf < 2; ++nf) b1v[nf] = b1h[c1_0 + nf * 16 + l16];
#pragma unroll
  for (int nf = 0; nf < 4; ++nf) b2v[nf] = b2h[c2_0 + nf * 16 + l16];
#pragma unroll
  for (int i = 0; i < 4; ++i) {
    len4[i] = lens[r0 + quad * 4 + i];
#pragma unroll
    for (int nf = 0; nf < 4; ++nf) h_own[nf][i] = 0.f;
  }
  __syncthreads();

  for (int t = 0; t < Sn; ++t) {
    // ---- GEMM1: C1[16,32-slice] = relu(h @ w1h + b1h), K=1024 split 4 ways
    f32x4 acc1[2] = {};
    const int kb1 = wave * 256;
#pragma unroll
    for (int kc = 0; kc < 8; ++kc) {
      int k0 = kb1 + kc * 32;
      f16x8 af = *(const f16x8*)&hbuf[(size_t)(r0 + l16) * Hn + k0 + quad * 8];
#pragma unroll
      for (int nf = 0; nf < 2; ++nf) {
        f16x8 bf = *(const f16x8*)&w1s[(nf * 16 + l16) * 1032 + k0 + quad * 8];
        acc1[nf] = __builtin_amdgcn_mfma_f32_16x16x32_f16(af, bf, acc1[nf], 0, 0, 0);
      }
    }
    if (wave > 0) {
#pragma unroll
      for (int nf = 0; nf < 2; ++nf)
        *(f32x4*)&red[(((wave - 1) * 2 + nf) * 16 + l16) * 24 + quad * 4] = acc1[nf];
    }
    __syncthreads();
    if (wave == 0) {
#pragma unroll
      for (int nf = 0; nf < 2; ++nf) {
        f32x4 s = acc1[nf];
#pragma unroll
        for (int p = 0; p < 3; ++p)
          s += *(const f32x4*)&red[((p * 2 + nf) * 16 + l16) * 24 + quad * 4];
#pragma unroll
        for (int i = 0; i < 4; ++i) {
          float v = s[i] + b1v[nf];
          v = fmaxf(v, 0.f);
          c1buf[(size_t)(r0 + quad * 4 + i) * HMn + c1_0 + nf * 16 + l16] = (f16)v;
        }
      }
    }
    __threadfence();
    __syncthreads();
    if (tid == 0) {
      __hip_atomic_fetch_add(ctr, 1, __ATOMIC_RELEASE, __HIP_MEMORY_SCOPE_AGENT);
      const int tgt = 32 * t + 16;
      while (__hip_atomic_load(ctr, __ATOMIC_ACQUIRE, __HIP_MEMORY_SCOPE_AGENT) < tgt)
        __builtin_amdgcn_s_sleep(1);
    }
    __syncthreads();

    // ---- GEMM2: hh[16,64-slice] = C1 @ w2h + b2h, K=512 split 4 ways
    f32x4 acc2[4] = {};
    const int kb2 = wave * 128;
#pragma unroll
    for (int kc = 0; kc < 4; ++kc) {
      int k0 = kb2 + kc * 32;
      f16x8 af = *(const f16x8*)&c1buf[(size_t)(r0 + l16) * HMn + k0 + quad * 8];
#pragma unroll
      for (int nf = 0; nf < 4; ++nf) {
        f16x8 bf = *(const f16x8*)&w2s[(nf * 16 + l16) * 520 + k0 + quad * 8];
        acc2[nf] = __builtin_amdgcn_mfma_f32_16x16x32_f16(af, bf, acc2[nf], 0, 0, 0);
      }
    }
    if (wave > 0) {
#pragma unroll
      for (int nf = 0; nf < 4; ++nf)
        *(f32x4*)&red[(((wave - 1) * 4 + nf) * 16 + l16) * 24 + quad * 4] = acc2[nf];
    }
    __syncthreads();
    if (wave == 0) {
#pragma unroll
      for (int nf = 0; nf < 4; ++nf) {
        f32x4 s = acc2[nf];
#pragma unroll
        for (int p = 0; p < 3; ++p)
          s += *(const f32x4*)&red[((p * 4 + nf) * 16 + l16) * 24 + quad * 4];
        const int col = c2_0 + nf * 16 + l16;
#pragma unroll
        for (int i = 0; i < 4; ++i) {
          const int rb = r0 + quad * 4 + i;
          size_t oidx = ((size_t)rb * Sn + t) * Hn + col;
          float pre = out[oidx] + s[i] + b2v[nf];
          float ex = __expf(2.f * pre);
          float nh = (ex - 1.f) / (ex + 1.f);
          float hv = (t < len4[i]) ? nh : h_own[nf][i];
          h_own[nf][i] = hv;
          out[oidx] = hv;
          hbuf[(size_t)rb * Hn + col] = (f16)hv;
        }
      }
    }
    __threadfence();
    __syncthreads();
    if (tid == 0) {
      __hip_atomic_fetch_add(ctr, 1, __ATOMIC_RELEASE, __HIP_MEMORY_SCOPE_AGENT);
      const int tgt = 32 * t + 32;
      while (__hip_atomic_load(ctr, __ATOMIC_ACQUIRE, __HIP_MEMORY_SCOPE_AGENT) < tgt)
        __builtin_amdgcn_s_sleep(1);
    }
    __syncthreads();
  }
}

// ---------------- launch ----------------

extern "C" void kernel_launch(void* const* d_in, const int* in_sizes, int n_in,
                              void* d_out, int out_size, void* d_ws, size_t ws_size,
                              hipStream_t stream) {
  (void)in_sizes; (void)n_in; (void)out_size; (void)ws_size;
  const float* seq = (const float*)d_in[0];
  const int* lens = (const int*)d_in[1];
  const float* w1x = (const float*)d_in[2];
  const float* b1x = (const float*)d_in[3];
  const float* w2x = (const float*)d_in[4];
  const float* b2x = (const float*)d_in[5];
  const float* w1h = (const float*)d_in[6];
  const float* b1h = (const float*)d_in[7];
  const float* w2h = (const float*)d_in[8];
  const float* b2h = (const float*)d_in[9];
  float* out = (float*)d_out;

  // ws layout (f16 elems): weights(T) | hbuf | c1buf | mid-chunk | ctrs
  f16* w1xT = (f16*)d_ws;              // [512][512]   (n,k)
  f16* w2xT = w1xT + 512 * 512;        // [1024][512]
  f16* w1hT = w2xT + 1024 * 512;       // [512][1024]
  f16* w2hT = w1hT + 512 * 1024;       // [1024][512]
  f16* hbuf = w2hT + 1024 * 512;       // [256][1024]
  f16* c1buf = hbuf + Bn * Hn;         // [256][512]
  f16* mid = c1buf + Bn * HMn;         // [16384][512] chunk scratch
  int* ctrs = (int*)(mid + (size_t)16384 * 512);  // [16][64]

  init_zero<<<128, 256, 0, stream>>>(hbuf, ctrs);
  transpose_cvt<<<(512 * 512) / 256, 256, 0, stream>>>(w1x, w1xT, 512, 512);
  transpose_cvt<<<(512 * 1024) / 256, 256, 0, stream>>>(w2x, w2xT, 512, 1024);
  transpose_cvt<<<(1024 * 512) / 256, 256, 0, stream>>>(w1h, w1hT, 1024, 512);
  transpose_cvt<<<(512 * 1024) / 256, 256, 0, stream>>>(w2h, w2hT, 512, 1024);

  const int Mtot = Bn * Sn;  // 131072
  const int Mch = 16384;     // chunk M so mid scratch stays small
  for (int c = 0; c < Mtot / Mch; ++c) {
    const float* Ac = seq + (size_t)c * Mch * En;
    gemm128<true, true, true><<<dim3(Mch / 128, HMn / 128), 256, 0, stream>>>(
        (const void*)Ac, w1xT, b1x, (void*)mid, Mch, HMn, En);
    float* Oc = out + (size_t)c * Mch * Hn;
    gemm128<false, false, false><<<dim3(Mch / 128, Hn / 128), 256, 0, stream>>>(
        (const void*)mid, w2xT, b2x, (void*)Oc, Mch, Hn, HMn);
  }

  hipFuncSetAttribute(reinterpret_cast<const void*>(recur),
                      hipFuncAttributeMaxDynamicSharedMemorySize, RECUR_SMEM);
  recur<<<256, 256, RECUR_SMEM, stream>>>(w1hT, w2hT, b1h, b2h, lens, hbuf, c1buf, out, ctrs);
}

// Round 2
// 5310.360 us; speedup vs baseline: 6.0456x; 6.0456x over previous
//
#include <hip/hip_runtime.h>

#define Bn 256
#define Sn 512
#define En 512
#define Hn 1024
#define HMn 512

typedef _Float16 f16;
typedef _Float16 f16x8 __attribute__((ext_vector_type(8)));
typedef _Float16 f16x4 __attribute__((ext_vector_type(4)));
typedef float f32x4 __attribute__((ext_vector_type(4)));

// ---------------- prep kernels ----------------

__global__ void transpose_cvt(const float* __restrict__ src, f16* __restrict__ dst, int R, int C) {
  int idx = blockIdx.x * 256 + threadIdx.x;
  if (idx >= R * C) return;
  int r = idx / C, c = idx % C;
  dst[(size_t)c * R + r] = (f16)src[idx];
}

__global__ void init_zero(f16* hbuf, int* ctrs) {
  int idx = blockIdx.x * 256 + threadIdx.x;
  if (idx < (Bn * Hn) / 8) ((uint4*)hbuf)[idx] = make_uint4(0u, 0u, 0u, 0u);
  if (idx < 16 * 64) ctrs[idx] = 0;
}

// ---------------- phase A: xh = relu(seq@w1x+b1x)@w2x+b2x ----------------

template <bool A_FP32, bool RELU, bool OUT_F16>
__global__ __launch_bounds__(256) void gemm128(
    const void* __restrict__ Av, const f16* __restrict__ BT,
    const float* __restrict__ bias, void* __restrict__ Cv,
    int M, int N, int K) {
  __shared__ f16 As[128][40];
  __shared__ f16 Bs[128][40];
  const int m0 = blockIdx.x * 128, n0 = blockIdx.y * 128;
  const int tid = threadIdx.x;
  const int wave = tid >> 6, lane = tid & 63, quad = lane >> 4, l16 = lane & 15;
  const int wm = (wave & 1) * 64, wn = (wave >> 1) * 64;

  f32x4 acc[4][4] = {};

  for (int k0 = 0; k0 < K; k0 += 32) {
    if (A_FP32) {
      const float* A = (const float*)Av;
#pragma unroll
      for (int i = 0; i < 4; ++i) {
        int slot = tid + i * 256;
        int row = slot >> 3, c4 = (slot & 7) * 4;
        float4 v = *(const float4*)(A + (size_t)(m0 + row) * K + k0 + c4);
        f16x4 h;
        h[0] = (f16)v.x; h[1] = (f16)v.y; h[2] = (f16)v.z; h[3] = (f16)v.w;
        *(f16x4*)&As[row][c4] = h;
      }
    } else {
      const f16* A = (const f16*)Av;
#pragma unroll
      for (int i = 0; i < 2; ++i) {
        int slot = tid + i * 256;
        int row = slot >> 2, c8 = (slot & 3) * 8;
        *(uint4*)&As[row][c8] = *(const uint4*)(A + (size_t)(m0 + row) * K + k0 + c8);
      }
    }
#pragma unroll
    for (int i = 0; i < 2; ++i) {
      int slot = tid + i * 256;
      int row = slot >> 2, c8 = (slot & 3) * 8;
      *(uint4*)&Bs[row][c8] = *(const uint4*)(BT + (size_t)(n0 + row) * K + k0 + c8);
    }
    __syncthreads();
    f16x8 af[4];
#pragma unroll
    for (int mi = 0; mi < 4; ++mi)
      af[mi] = *(const f16x8*)&As[wm + mi * 16 + l16][quad * 8];
#pragma unroll
    for (int ni = 0; ni < 4; ++ni) {
      f16x8 bf = *(const f16x8*)&Bs[wn + ni * 16 + l16][quad * 8];
#pragma unroll
      for (int mi = 0; mi < 4; ++mi)
        acc[mi][ni] = __builtin_amdgcn_mfma_f32_16x16x32_f16(af[mi], bf, acc[mi][ni], 0, 0, 0);
    }
    __syncthreads();
  }
#pragma unroll
  for (int ni = 0; ni < 4; ++ni) {
    int col = n0 + wn + ni * 16 + l16;
    float bv = bias[col];
#pragma unroll
    for (int mi = 0; mi < 4; ++mi) {
#pragma unroll
      for (int r = 0; r < 4; ++r) {
        int grow = m0 + wm + mi * 16 + quad * 4 + r;
        float v = acc[mi][ni][r] + bv;
        if (RELU) v = fmaxf(v, 0.f);
        if (OUT_F16)
          ((f16*)Cv)[(size_t)grow * N + col] = (f16)v;
        else
          ((float*)Cv)[(size_t)grow * N + col] = v;
      }
    }
  }
}

// ---------------- phase B: the recurrence ----------------
// 16 groups x 16 members. Weight slices LDS-resident. Cross-WG exchange via
// write-through (sc0 sc1) relaxed atomic stores -> coherence point; barrier is
// relaxed add + relaxed poll + ONE acquire fence (no per-poll buffer_inv, no
// buffer_wbl2 anywhere). Epilogues distributed across waves; xh prefetched.

#define W1S_ELEMS (32 * 1032)
#define W2S_ELEMS (64 * 520)
#define RED_OFF (W1S_ELEMS * 2 + W2S_ELEMS * 2)
#define RECUR_SMEM (RED_OFF + 16 * 16 * 20 * 4)

__device__ __forceinline__ void st_coh_f16(f16* p, f16 v) {
  __hip_atomic_store((unsigned short*)p, __builtin_bit_cast(unsigned short, v),
                     __ATOMIC_RELAXED, __HIP_MEMORY_SCOPE_AGENT);
}
__device__ __forceinline__ void st_coh_f32(float* p, float v) {
  __hip_atomic_store(p, v, __ATOMIC_RELAXED, __HIP_MEMORY_SCOPE_AGENT);
}

__device__ __forceinline__ void gbar(int* ctr, int tgt) {
  __syncthreads();  // drains vmcnt: sc1 stores are at the coherence point
  if (threadIdx.x == 0) {
    __hip_atomic_fetch_add(ctr, 1, __ATOMIC_RELAXED, __HIP_MEMORY_SCOPE_AGENT);
    while (__hip_atomic_load(ctr, __ATOMIC_RELAXED, __HIP_MEMORY_SCOPE_AGENT) < tgt)
      __builtin_amdgcn_s_sleep(1);
    __builtin_amdgcn_fence(__ATOMIC_ACQUIRE, "agent");  // one buffer_inv
  }
  __syncthreads();
}

__global__ __launch_bounds__(256, 1) void recur(
    const f16* __restrict__ w1hT, const f16* __restrict__ w2hT,
    const float* __restrict__ b1h, const float* __restrict__ b2h,
    const int* __restrict__ lens,
    f16* hbuf, f16* c1buf, float* out, int* ctrs) {
  extern __shared__ char smem[];
  f16* w1s = (f16*)smem;                   // [32][1032]
  f16* w2s = (f16*)(smem + W1S_ELEMS * 2); // [64][520]
  float* red = (float*)(smem + RED_OFF);   // [16 slots][16][20]

  const int g = blockIdx.x & 15, j = blockIdx.x >> 4;
  const int r0 = g * 16, c1_0 = j * 32, c2_0 = j * 64;
  const int tid = threadIdx.x, wave = tid >> 6, lane = tid & 63;
  const int quad = lane >> 4, l16 = lane & 15;
  int* ctr = ctrs + g * 64;

  // load weight slices into LDS once
#pragma unroll
  for (int i = 0; i < 16; ++i) {
    int slot = tid + i * 256;
    int row = slot >> 7, c8 = (slot & 127) * 8;
    *(uint4*)&w1s[row * 1032 + c8] = *(const uint4*)&w1hT[(size_t)(c1_0 + row) * 1024 + c8];
  }
#pragma unroll
  for (int i = 0; i < 16; ++i) {
    int slot = tid + i * 256;
    int row = slot >> 6, c8 = (slot & 63) * 8;
    *(uint4*)&w2s[row * 520 + c8] = *(const uint4*)&w2hT[(size_t)(c2_0 + row) * 512 + c8];
  }

  const float b1v = (wave < 2) ? b1h[c1_0 + wave * 16 + l16] : 0.f;
  const float b2v = b2h[c2_0 + wave * 16 + l16];
  int len4[4];
  float h_own[4];
#pragma unroll
  for (int i = 0; i < 4; ++i) {
    len4[i] = lens[r0 + quad * 4 + i];
    h_own[i] = 0.f;
  }
  __syncthreads();

  for (int t = 0; t < Sn; ++t) {
    // prefetch this wave's xh slice (consumed 2 barriers later)
    float xh[4];
#pragma unroll
    for (int i = 0; i < 4; ++i)
      xh[i] = out[((size_t)(r0 + quad * 4 + i) * Sn + t) * Hn + c2_0 + wave * 16 + l16];

    // ---- GEMM1: C1[16 x 32-slice] = relu(h @ w1h + b1h), K=1024 / 4 waves
    f32x4 acc1[2] = {};
    const int kb1 = wave * 256;
#pragma unroll
    for (int kc = 0; kc < 8; ++kc) {
      int k0 = kb1 + kc * 32;
      f16x8 af = *(const f16x8*)&hbuf[(size_t)(r0 + l16) * Hn + k0 + quad * 8];
#pragma unroll
      for (int nf = 0; nf < 2; ++nf) {
        f16x8 bf = *(const f16x8*)&w1s[(nf * 16 + l16) * 1032 + k0 + quad * 8];
        acc1[nf] = __builtin_amdgcn_mfma_f32_16x16x32_f16(af, bf, acc1[nf], 0, 0, 0);
      }
    }
#pragma unroll
    for (int nf = 0; nf < 2; ++nf)
      *(f32x4*)&red[((wave * 2 + nf) * 16 + l16) * 20 + quad * 4] = acc1[nf];
    __syncthreads();
    if (wave < 2) {  // waves 0,1 reduce + store one 16-col frag each
      const int nf = wave;
      f32x4 s = *(const f32x4*)&red[(nf * 16 + l16) * 20 + quad * 4];
#pragma unroll
      for (int p = 1; p < 4; ++p)
        s += *(const f32x4*)&red[((p * 2 + nf) * 16 + l16) * 20 + quad * 4];
#pragma unroll
      for (int i = 0; i < 4; ++i) {
        float v = fmaxf(s[i] + b1v, 0.f);
        st_coh_f16(&c1buf[(size_t)(r0 + quad * 4 + i) * HMn + c1_0 + nf * 16 + l16], (f16)v);
      }
    }
    gbar(ctr, 32 * t + 16);

    // ---- GEMM2: hh[16 x 64-slice] = C1 @ w2h + b2h, K=512 / 4 waves
    f32x4 acc2[4] = {};
    const int kb2 = wave * 128;
#pragma unroll
    for (int kc = 0; kc < 4; ++kc) {
      int k0 = kb2 + kc * 32;
      f16x8 af = *(const f16x8*)&c1buf[(size_t)(r0 + l16) * HMn + k0 + quad * 8];
#pragma unroll
      for (int nf = 0; nf < 4; ++nf) {
        f16x8 bf = *(const f16x8*)&w2s[(nf * 16 + l16) * 520 + k0 + quad * 8];
        acc2[nf] = __builtin_amdgcn_mfma_f32_16x16x32_f16(af, bf, acc2[nf], 0, 0, 0);
      }
    }
#pragma unroll
    for (int nf = 0; nf < 4; ++nf)
      *(f32x4*)&red[((wave * 4 + nf) * 16 + l16) * 20 + quad * 4] = acc2[nf];
    __syncthreads();
    {  // each wave reduces + epilogues its own 16-col frag
      const int nf = wave;
      f32x4 s = *(const f32x4*)&red[(nf * 16 + l16) * 20 + quad * 4];
#pragma unroll
      for (int p = 1; p < 4; ++p)
        s += *(const f32x4*)&red[((p * 4 + nf) * 16 + l16) * 20 + quad * 4];
      const int col = c2_0 + nf * 16 + l16;
#pragma unroll
      for (int i = 0; i < 4; ++i) {
        const int rb = r0 + quad * 4 + i;
        float pre = xh[i] + s[i] + b2v;
        float ex = __expf(2.f * pre);
        float nh = (ex - 1.f) / (ex + 1.f);
        float hv = (t < len4[i]) ? nh : h_own[i];
        h_own[i] = hv;
        st_coh_f32(&out[((size_t)rb * Sn + t) * Hn + col], hv);
        st_coh_f16(&hbuf[(size_t)rb * Hn + col], (f16)hv);
      }
    }
    gbar(ctr, 32 * t + 32);
  }
}

// ---------------- launch ----------------

extern "C" void kernel_launch(void* const* d_in, const int* in_sizes, int n_in,
                              void* d_out, int out_size, void* d_ws, size_t ws_size,
                              hipStream_t stream) {
  (void)in_sizes; (void)n_in; (void)out_size; (void)ws_size;
  const float* seq = (const float*)d_in[0];
  const int* lens = (const int*)d_in[1];
  const float* w1x = (const float*)d_in[2];
  const float* b1x = (const float*)d_in[3];
  const float* w2x = (const float*)d_in[4];
  const float* b2x = (const float*)d_in[5];
  const float* w1h = (const float*)d_in[6];
  const float* b1h = (const float*)d_in[7];
  const float* w2h = (const float*)d_in[8];
  const float* b2h = (const float*)d_in[9];
  float* out = (float*)d_out;

  f16* w1xT = (f16*)d_ws;              // [512][512]
  f16* w2xT = w1xT + 512 * 512;        // [1024][512]
  f16* w1hT = w2xT + 1024 * 512;       // [512][1024]
  f16* w2hT = w1hT + 512 * 1024;       // [1024][512]
  f16* hbuf = w2hT + 1024 * 512;       // [256][1024]
  f16* c1buf = hbuf + Bn * Hn;         // [256][512]
  f16* mid = c1buf + Bn * HMn;         // [16384][512] chunk scratch
  int* ctrs = (int*)(mid + (size_t)16384 * 512);  // [16][64]

  init_zero<<<128, 256, 0, stream>>>(hbuf, ctrs);
  transpose_cvt<<<(512 * 512) / 256, 256, 0, stream>>>(w1x, w1xT, 512, 512);
  transpose_cvt<<<(512 * 1024) / 256, 256, 0, stream>>>(w2x, w2xT, 512, 1024);
  transpose_cvt<<<(1024 * 512) / 256, 256, 0, stream>>>(w1h, w1hT, 1024, 512);
  transpose_cvt<<<(512 * 1024) / 256, 256, 0, stream>>>(w2h, w2hT, 512, 1024);

  const int Mtot = Bn * Sn;  // 131072
  const int Mch = 16384;
  for (int c = 0; c < Mtot / Mch; ++c) {
    const float* Ac = seq + (size_t)c * Mch * En;
    gemm128<true, true, true><<<dim3(Mch / 128, HMn / 128), 256, 0, stream>>>(
        (const void*)Ac, w1xT, b1x, (void*)mid, Mch, HMn, En);
    float* Oc = out + (size_t)c * Mch * Hn;
    gemm128<false, false, false><<<dim3(Mch / 128, Hn / 128), 256, 0, stream>>>(
        (const void*)mid, w2xT, b2x, (void*)Oc, Mch, Hn, HMn);
  }

  hipFuncSetAttribute(reinterpret_cast<const void*>(recur),
                      hipFuncAttributeMaxDynamicSharedMemorySize, RECUR_SMEM);
  recur<<<256, 256, RECUR_SMEM, stream>>>(w1hT, w2hT, b1h, b2h, lens, hbuf, c1buf, out, ctrs);
}